// Round 11
// baseline (63.250 us; speedup 1.0000x reference)
//
#include <hip/hip_runtime.h>

#define NB 32
#define NN 64
#define ND 128
#define NH 256
#define LN_EPS 1e-5f
#define RP 4

typedef __attribute__((ext_vector_type(8))) short bf16x8;
typedef __attribute__((ext_vector_type(4))) float f32x4;

// ---- branchless erf-based GELU, A&S 7.1.25 (|erf err| <= 5e-4), Estrin form ----
__device__ __forceinline__ float gelu2(float x) {     // returns 2*gelu(x)
    const float au  = fabsf(x);
    const float xpa = x + au;
    const float z   = au * 0.70710678118654752440f;
    const float z2  = z * z;
    const float pc  = fmaf(0.078108f, z, 0.000972f);
    const float pb  = fmaf(0.278393f, z, 1.0f);
    const float p   = fmaf(z2, fmaf(z, pc, 0.230389f), pb);
    const float p2  = p * p;
    const float r   = __builtin_amdgcn_rcpf(p2 * p2);
    return fmaf(-au, r, xpa);
}
__device__ __forceinline__ float gelu_h(float x) { return 0.5f * gelu2(x); }

__device__ __forceinline__ short f2bf(float f) {      // RNE float->bf16
    unsigned u = __float_as_uint(f);
    u += 0x7FFFu + ((u >> 16) & 1u);
    return (short)(u >> 16);
}

// ---------------- K1: [0..511] Pt/Qm/XW/Pb/Qb + rowstats ; [512..580] WCbT/v/Wn2bT ----------------
__global__ __launch_bounds__(256) void k_pre(const float* __restrict__ slots,
                                             const float* __restrict__ We1,
                                             const float* __restrict__ be1,
                                             const float* __restrict__ Wn1,
                                             const float* __restrict__ We2,
                                             const float* __restrict__ be2,
                                             const float* __restrict__ Wn2,
                                             float* __restrict__ Pt,
                                             float* __restrict__ Qm,
                                             float* __restrict__ XW,
                                             short* __restrict__ Pb,
                                             short* __restrict__ Qb,
                                             float4* __restrict__ rowstats,
                                             short* __restrict__ WCbT,
                                             float* __restrict__ v,
                                             short* __restrict__ Wn2bT) {
    __shared__ float xs[RP][ND];
    __shared__ float red[4][RP][4];
    const int t = threadIdx.x;

    if (blockIdx.x >= 512) {           // ---- prep role ----
        const int bid2 = blockIdx.x - 512;
        if (bid2 == 64) {              // v = be2 @ Wn1_bot
            __shared__ float bs[ND];
            if (t < ND) bs[t] = be2[t];
            __syncthreads();
            float acc = 0.f;
            #pragma unroll 4
            for (int d = 0; d < ND; ++d) acc = fmaf(bs[d], Wn1[(ND + d) * NH + t], acc);
            v[t] = acc;
            return;
        }
        if (bid2 > 64) {               // Wn2bT[c][k] = Wn2[k][c], bf16
            const int c0 = (bid2 - 65) * 32;
            for (int ci = 0; ci < 32; ++ci) {
                const int c = c0 + ci;
                Wn2bT[(size_t)c * NH + t] = f2bf(Wn2[(size_t)t * ND + c]);
            }
            return;
        }
        const int k0 = bid2 * 4;       // WC rows k0..k0+3 -> WCbT cols
        __shared__ float ws[4][ND];
        #pragma unroll
        for (int i = 0; i < 2; ++i) {
            const int idx = t + i * 256;
            ws[idx >> 7][idx & 127] = We2[(k0 + (idx >> 7)) * ND + (idx & 127)];
        }
        __syncthreads();
        float acc[4] = {0.f, 0.f, 0.f, 0.f};
        #pragma unroll 4
        for (int d = 0; d < ND; ++d) {
            const float wn = Wn1[(ND + d) * NH + t];
            #pragma unroll
            for (int r = 0; r < 4; ++r) acc[r] = fmaf(ws[r][d], wn, acc[r]);
        }
        short4 pk;
        pk.x = f2bf(acc[0]); pk.y = f2bf(acc[1]);
        pk.z = f2bf(acc[2]); pk.w = f2bf(acc[3]);
        *(short4*)(WCbT + (size_t)t * NH + k0) = pk;
        return;
    }

    // ---- pq role ----
    const int r0 = blockIdx.x * RP;
    const int lane = t & 63, wave = t >> 6;
    #pragma unroll
    for (int i = 0; i < 2; ++i) {
        const int idx = t + i * 256;
        xs[idx >> 7][idx & 127] = slots[(size_t)(r0 + (idx >> 7)) * ND + (idx & 127)];
    }
    __syncthreads();
    float pt[RP], qq[RP], xw[RP];
    const float bb = be1[t];
    #pragma unroll
    for (int r = 0; r < RP; ++r) { pt[r] = bb; qq[r] = 0.f; xw[r] = 0.f; }
    #pragma unroll 4
    for (int d = 0; d < ND; ++d) {
        const float wt  = We1[d * NH + t];
        const float wbt = We1[(ND + d) * NH + t];
        const float wn  = Wn1[d * NH + t];
        #pragma unroll
        for (int r = 0; r < RP; ++r) {
            const float x = xs[r][d];
            pt[r] = fmaf(x, wt,  pt[r]);
            qq[r] = fmaf(x, wbt, qq[r]);
            xw[r] = fmaf(x, wn,  xw[r]);
        }
    }
    #pragma unroll
    for (int r = 0; r < RP; ++r) {
        const size_t row = (size_t)(r0 + r);
        Pt[row * NH + t] = pt[r];
        Qm[row * NH + t] = qq[r];
        XW[row * NH + t] = xw[r];
        Pb[row * NH + t] = f2bf(pt[r]);
        Qb[row * NH + t] = f2bf(qq[r]);
    }
    float s1[RP], s2[RP], s3[RP], s4[RP];
    #pragma unroll
    for (int r = 0; r < RP; ++r) {
        s1[r] = pt[r]; s2[r] = pt[r] * pt[r];
        s3[r] = qq[r]; s4[r] = qq[r] * qq[r];
    }
    #pragma unroll
    for (int off = 32; off; off >>= 1) {
        #pragma unroll
        for (int r = 0; r < RP; ++r) {
            s1[r] += __shfl_xor(s1[r], off);
            s2[r] += __shfl_xor(s2[r], off);
            s3[r] += __shfl_xor(s3[r], off);
            s4[r] += __shfl_xor(s4[r], off);
        }
    }
    if (lane == 0) {
        #pragma unroll
        for (int r = 0; r < RP; ++r) {
            red[wave][r][0] = s1[r]; red[wave][r][1] = s2[r];
            red[wave][r][2] = s3[r]; red[wave][r][3] = s4[r];
        }
    }
    __syncthreads();
    if (t < RP) {
        float4 st;
        st.x = (red[0][t][0] + red[1][t][0]) + (red[2][t][0] + red[3][t][0]);
        st.y = (red[0][t][1] + red[1][t][1]) + (red[2][t][1] + red[3][t][1]);
        st.z = (red[0][t][2] + red[1][t][2]) + (red[2][t][2] + red[3][t][2]);
        st.w = (red[0][t][3] + red[1][t][3]) + (red[2][t][3] + red[3][t][3]);
        rowstats[r0 + t] = st;
    }
}

// ---------------- K2: MFMA dot -> wmr table {0.5w, rr, -mu*rr, w} ----------------
__global__ __launch_bounds__(256) void k_dot(
    const short* __restrict__ Pb, const short* __restrict__ Qb,
    const float4* __restrict__ rowstats,
    const float* __restrict__ adj,
    float4* __restrict__ wmrG)
{
    const int b  = blockIdx.x >> 2;
    const int jt = blockIdx.x & 3;
    const int t  = threadIdx.x;
    const int l  = t & 63;
    const int i0 = (t >> 6) * 16;
    const int j0 = jt * 16;
    const int rA = l & 15;
    const int kg = l >> 4;

    const short* Prow = Pb + ((size_t)b * NN + i0 + rA) * NH + kg * 8;
    const short* Qrow = Qb + ((size_t)b * NN + j0 + rA) * NH + kg * 8;
    f32x4 acc = {0.f, 0.f, 0.f, 0.f};
    #pragma unroll
    for (int kc = 0; kc < 8; ++kc) {
        const bf16x8 av = *(const bf16x8*)(Prow + kc * 32);
        const bf16x8 bv = *(const bf16x8*)(Qrow + kc * 32);
        acc = __builtin_amdgcn_mfma_f32_16x16x32_bf16(av, bv, acc, 0, 0, 0);
    }
    const int j  = j0 + rA;
    const int gj = b * NN + j;
    const float4 stj = rowstats[gj];
    const float inv = 1.0f / NH;
    #pragma unroll
    for (int q = 0; q < 4; ++q) {
        const int i  = i0 + kg * 4 + q;
        const int gi = b * NN + i;
        const float4 sti = rowstats[gi];
        float a = adj[(size_t)gi * NN + j];
        if (j == i) a = 0.f;
        const float cd = acc[q];
        const float mu = (sti.x + stj.z) * inv;
        const float e2 = fmaf(2.f, cd, sti.y + stj.w) * inv;
        const float rr = __builtin_amdgcn_rsqf(fmaf(-mu, mu, e2) + LN_EPS);
        wmrG[(size_t)gi * NN + j] = make_float4(0.5f * a, rr, -mu * rr, a);
    }
}

// ---------------- K3: edge loop only, 1 row/block, 2048 blocks (8/CU) ----------------
__global__ __launch_bounds__(256, 8) void k_msg(
    const float* __restrict__ Pt,
    const float* __restrict__ Qm,
    const float4* __restrict__ wmrG,
    const float* __restrict__ ge,  const float* __restrict__ bge,
    short* __restrict__ Sb, float* __restrict__ wsumw)
{
    __shared__ float4 wmr[NN];
    __shared__ float  s[4][NH];

    const int row = blockIdx.x;
    const int b   = row >> 6;
    const int t   = threadIdx.x;
    const int lane = t & 63;
    const int wave = t >> 6;

    if (t < NN) wmr[t] = wmrG[(size_t)row * NN + t];
    const float4 P  = ((const float4*)(Pt + (size_t)row * NH))[lane];
    const float4 G  = ((const float4*)ge)[lane];
    const float4 Bg = ((const float4*)bge)[lane];
    __syncthreads();

    if (wave == 0) {                  // wsum, off critical path
        float wv = wmr[lane].w;
        #pragma unroll
        for (int off = 32; off; off >>= 1) wv += __shfl_xor(wv, off);
        if (lane == 0) wsumw[row] = wv;
    }

    const float4* Qb4 = (const float4*)(Qm + (size_t)b * NN * NH) + lane;
    float4 A = make_float4(0.f, 0.f, 0.f, 0.f);
    #pragma unroll 4
    for (int k = 0; k < 16; ++k) {
        const int jj = wave + 4 * k;
        const float4 q = Qb4[jj * (NH / 4)];
        const float4 m = wmr[jj];
        float h, uu;
        h = P.x + q.x; uu = fmaf(fmaf(h, m.y, m.z), G.x, Bg.x); A.x = fmaf(m.x, gelu2(uu), A.x);
        h = P.y + q.y; uu = fmaf(fmaf(h, m.y, m.z), G.y, Bg.y); A.y = fmaf(m.x, gelu2(uu), A.y);
        h = P.z + q.z; uu = fmaf(fmaf(h, m.y, m.z), G.z, Bg.z); A.z = fmaf(m.x, gelu2(uu), A.z);
        h = P.w + q.w; uu = fmaf(fmaf(h, m.y, m.z), G.w, Bg.w); A.w = fmaf(m.x, gelu2(uu), A.w);
    }
    ((float4*)s[wave])[lane] = A;
    __syncthreads();
    const float Sf = (s[0][t] + s[1][t]) + (s[2][t] + s[3][t]);
    Sb[(size_t)row * NH + t] = f2bf(Sf);
}

// ---------------- K4: node MLP via MFMA, 16 rows/block, 128 blocks ----------------
#define HS 261
__global__ __launch_bounds__(256) void k_node(
    const float* __restrict__ slots,
    const short* __restrict__ Sb,
    const float* __restrict__ wsumw,
    const float* __restrict__ XW,
    const short* __restrict__ WCbT,
    const float* __restrict__ v,
    const float* __restrict__ bn1,
    const float* __restrict__ gn,  const float* __restrict__ bgn,
    const short* __restrict__ Wn2bT,
    const float* __restrict__ bn2,
    float* __restrict__ out)
{
    __shared__ float lds_h[16][HS];        // padded: conflict-free row stripes
    __shared__ short lds_g[16][264];       // bf16, 528B row stride (16B-aligned)
    __shared__ float red1[16][16], red2[16][16];
    __shared__ float lds_mr[16][2];

    const int r0 = blockIdx.x * 16;
    const int t  = threadIdx.x;
    const int l  = t & 63;
    const int w  = t >> 6;
    const int rA = l & 15;
    const int kg = l >> 4;
    const int orow = kg * 4;

    // A-fragments: S rows (bf16)
    bf16x8 afr[8];
    {
        const short* Arow = Sb + (size_t)(r0 + rA) * NH + kg * 8;
        #pragma unroll
        for (int kc = 0; kc < 8; ++kc) afr[kc] = *(const bf16x8*)(Arow + kc * 32);
    }

    // GEMM1: h1 = S @ WC^T(+fold)  — 4 col-tiles per wave
    #pragma unroll
    for (int cti = 0; cti < 4; ++cti) {
        const int ct = w * 4 + cti;
        const short* Brow = WCbT + (size_t)(ct * 16 + rA) * NH + kg * 8;
        f32x4 acc = {0.f, 0.f, 0.f, 0.f};
        #pragma unroll
        for (int kc = 0; kc < 8; ++kc) {
            const bf16x8 bv = *(const bf16x8*)(Brow + kc * 32);
            acc = __builtin_amdgcn_mfma_f32_16x16x32_bf16(afr[kc], bv, acc, 0, 0, 0);
        }
        const int col = ct * 16 + rA;
        const float vc = v[col], b1 = bn1[col];
        #pragma unroll
        for (int q = 0; q < 4; ++q) {
            const int row = orow + q;
            lds_h[row][col] = acc[q] + XW[(size_t)(r0 + row) * NH + col]
                            + fmaf(wsumw[r0 + row], vc, b1);
        }
    }
    __syncthreads();

    // LN stats: row = t&15, 16-channel chunk = t>>4
    {
        const int row = t & 15, grp = t >> 4;
        float s1 = 0.f, s2 = 0.f;
        #pragma unroll
        for (int c = grp * 16; c < grp * 16 + 16; ++c) {
            const float h = lds_h[row][c];
            s1 += h; s2 = fmaf(h, h, s2);
        }
        red1[row][grp] = s1; red2[row][grp] = s2;
    }
    __syncthreads();
    if (t < 16) {
        float S1 = 0.f, S2 = 0.f;
        #pragma unroll
        for (int g = 0; g < 16; ++g) { S1 += red1[t][g]; S2 += red2[t][g]; }
        const float mu  = S1 * (1.0f / NH);
        const float var = fmaf(-mu, mu, S2 * (1.0f / NH));
        lds_mr[t][0] = mu;
        lds_mr[t][1] = __builtin_amdgcn_rsqf(var + LN_EPS);
    }
    __syncthreads();
    {
        const float gc = gn[t], bgc = bgn[t];
        #pragma unroll
        for (int r = 0; r < 16; ++r) {
            const float rr = lds_mr[r][1];
            const float u0 = fmaf(lds_h[r][t], rr, -lds_mr[r][0] * rr);
            lds_g[r][t] = f2bf(gelu_h(fmaf(u0, gc, bgc)));
        }
    }
    __syncthreads();

    // GEMM2: delta = g @ Wn2^T — 2 col-tiles per wave
    #pragma unroll
    for (int cti = 0; cti < 2; ++cti) {
        const int ct = w * 2 + cti;
        const short* Brow = Wn2bT + (size_t)(ct * 16 + rA) * NH + kg * 8;
        f32x4 acc = {0.f, 0.f, 0.f, 0.f};
        #pragma unroll
        for (int kc = 0; kc < 8; ++kc) {
            const bf16x8 av = *(const bf16x8*)(&lds_g[rA][kg * 8 + kc * 32]);
            const bf16x8 bv = *(const bf16x8*)(Brow + kc * 32);
            acc = __builtin_amdgcn_mfma_f32_16x16x32_bf16(av, bv, acc, 0, 0, 0);
        }
        const int col = ct * 16 + rA;
        const float b2 = bn2[col];
        #pragma unroll
        for (int q = 0; q < 4; ++q) {
            const int row = orow + q;
            const size_t o = (size_t)(r0 + row) * ND + col;
            out[o] = slots[o] + b2 + acc[q];
        }
    }
}

extern "C" void kernel_launch(void* const* d_in, const int* in_sizes, int n_in,
                              void* d_out, int out_size, void* d_ws, size_t ws_size,
                              hipStream_t stream) {
    const float* slots = (const float*)d_in[0];
    const float* adj   = (const float*)d_in[1];
    const float* We1   = (const float*)d_in[2];
    const float* be1   = (const float*)d_in[3];
    const float* ge    = (const float*)d_in[4];
    const float* bge   = (const float*)d_in[5];
    const float* We2   = (const float*)d_in[6];
    const float* be2   = (const float*)d_in[7];
    const float* Wn1   = (const float*)d_in[8];
    const float* bn1   = (const float*)d_in[9];
    const float* gn    = (const float*)d_in[10];
    const float* bgn   = (const float*)d_in[11];
    const float* Wn2   = (const float*)d_in[12];
    const float* bn2   = (const float*)d_in[13];
    float* out = (float*)d_out;

    const size_t RN = (size_t)NB * NN;        // 2048
    float*  Ptw    = (float*)d_ws;            // [2048,256] f32
    float*  Qw     = Ptw  + RN * NH;          // [2048,256] f32
    float*  XWw    = Qw   + RN * NH;          // [2048,256] f32
    float*  vw     = XWw  + RN * NH;          // [256]
    float*  wsumw  = vw   + NH;               // [2048]
    float4* rsw    = (float4*)(wsumw + RN);   // [2048] (16B aligned)
    float4* wmrw   = rsw + RN;                // [2048*64]
    short*  Pbw    = (short*)(wmrw + RN * NN);// [2048,256] bf16
    short*  Qbw    = Pbw  + RN * NH;          // [2048,256] bf16
    short*  Sbw    = Qbw  + RN * NH;          // [2048,256] bf16
    short*  WCbTw  = Sbw  + RN * NH;          // [256,256]  bf16 (transposed)
    short*  Wn2bTw = WCbTw + (size_t)NH * NH; // [128,256]  bf16 (transposed)

    k_pre <<<581,             256, 0, stream>>>(slots, We1, be1, Wn1, We2, be2, Wn2,
                                                Ptw, Qw, XWw, Pbw, Qbw, rsw, WCbTw, vw, Wn2bTw);
    k_dot <<<NB * 4,          256, 0, stream>>>(Pbw, Qbw, rsw, adj, wmrw);
    k_msg <<<(int)RN,         256, 0, stream>>>(Ptw, Qw, wmrw, ge, bge, Sbw, wsumw);
    k_node<<<(int)(RN / 16),  256, 0, stream>>>(slots, Sbw, wsumw, XWw, WCbTw, vw,
                                                bn1, gn, bgn, Wn2bTw, bn2, out);
}

// Round 12
// 60.272 us; speedup vs baseline: 1.0494x; 1.0494x over previous
//
#include <hip/hip_runtime.h>

#define NB 32
#define NN 64
#define ND 128
#define NH 256
#define LN_EPS 1e-5f

typedef __attribute__((ext_vector_type(8))) short bf16x8;
typedef __attribute__((ext_vector_type(4))) float f32x4;

// ---- branchless erf-based GELU, A&S 7.1.25 (|erf err| <= 5e-4), Estrin form ----
__device__ __forceinline__ float gelu2(float x) {     // returns 2*gelu(x)
    const float au  = fabsf(x);
    const float xpa = x + au;
    const float z   = au * 0.70710678118654752440f;
    const float z2  = z * z;
    const float pc  = fmaf(0.078108f, z, 0.000972f);
    const float pb  = fmaf(0.278393f, z, 1.0f);
    const float p   = fmaf(z2, fmaf(z, pc, 0.230389f), pb);
    const float p2  = p * p;
    const float r   = __builtin_amdgcn_rcpf(p2 * p2);
    return fmaf(-au, r, xpa);
}
__device__ __forceinline__ float gelu_h(float x) { return 0.5f * gelu2(x); }

__device__ __forceinline__ short f2bf(float f) {      // RNE float->bf16
    unsigned u = __float_as_uint(f);
    u += 0x7FFFu + ((u >> 16) & 1u);
    return (short)(u >> 16);
}

// ---------------- K0: prep — WC f32, v, WT bf16 (3 transposed weight halves) ----------------
// blocks 0..63: WC rows ; block 64: v ; blocks 65..88: WT transpose
__global__ __launch_bounds__(256) void k_prep(const float* __restrict__ We1,
                                              const float* __restrict__ Wn1,
                                              const float* __restrict__ We2,
                                              const float* __restrict__ be2,
                                              float* __restrict__ WC,
                                              float* __restrict__ v,
                                              short* __restrict__ WT) {
    const int t = threadIdx.x;
    const int bid = blockIdx.x;
    if (bid < 64) {                    // WC = We2 @ Wn1_bot (f32)
        const int k0 = bid * 4;
        __shared__ float ws[4][ND];
        #pragma unroll
        for (int i = 0; i < 2; ++i) {
            const int idx = t + i * 256;
            ws[idx >> 7][idx & 127] = We2[(k0 + (idx >> 7)) * ND + (idx & 127)];
        }
        __syncthreads();
        float acc[4] = {0.f, 0.f, 0.f, 0.f};
        #pragma unroll 4
        for (int d = 0; d < ND; ++d) {
            const float wn = Wn1[(ND + d) * NH + t];
            #pragma unroll
            for (int r = 0; r < 4; ++r) acc[r] = fmaf(ws[r][d], wn, acc[r]);
        }
        #pragma unroll
        for (int r = 0; r < 4; ++r) WC[(k0 + r) * NH + t] = acc[r];
        return;
    }
    if (bid == 64) {                   // v = be2 @ Wn1_bot
        __shared__ float bs[ND];
        if (t < ND) bs[t] = be2[t];
        __syncthreads();
        float acc = 0.f;
        #pragma unroll 4
        for (int d = 0; d < ND; ++d) acc = fmaf(bs[d], Wn1[(ND + d) * NH + t], acc);
        v[t] = acc;
        return;
    }
    // transpose role: WT[m][col][d] = src_m[d][col] bf16
    const int r   = bid - 65;          // 0..23
    const int m   = r >> 3;            // 0..2
    const int c0  = (r & 7) * 32;
    const int col = c0 + (t & 31);
    const int d0  = (t >> 5) * 16;
    const float* src = (m == 0) ? We1 : (m == 1) ? (We1 + ND * NH) : Wn1;
    short* dst = WT + ((size_t)m * NH + col) * ND + d0;
    #pragma unroll 4
    for (int i = 0; i < 16; ++i)
        dst[i] = f2bf(src[(size_t)(d0 + i) * NH + col]);
}

// ---------------- K1: MFMA front GEMM — Pt/Qm/XW (+Pb/Qb bf16) + rowstats ----------------
// 128 blocks x 16 rows. Same verified fragment pattern as R11 k_node GEMM1.
__global__ __launch_bounds__(256) void k_pmm(const float* __restrict__ slots,
                                             const float* __restrict__ be1,
                                             const short* __restrict__ WT,
                                             float* __restrict__ Pt,
                                             float* __restrict__ Qm,
                                             float* __restrict__ XW,
                                             short* __restrict__ Pb,
                                             short* __restrict__ Qb,
                                             float4* __restrict__ rowstats) {
    __shared__ float lds_h[16][264];
    __shared__ float red1[16][16], red2[16][16];
    __shared__ float stP1[16], stP2[16], stQ1[16], stQ2[16];

    const int r0 = blockIdx.x * 16;
    const int t  = threadIdx.x;
    const int l  = t & 63;
    const int w  = t >> 6;
    const int rA = l & 15;
    const int kg = l >> 4;

    // A-fragments: slots rows (f32 -> bf16)
    bf16x8 afr[4];
    {
        const float* srow = slots + (size_t)(r0 + rA) * ND + kg * 8;
        #pragma unroll
        for (int kc = 0; kc < 4; ++kc) {
            const float4 a = *(const float4*)(srow + kc * 32);
            const float4 b = *(const float4*)(srow + kc * 32 + 4);
            bf16x8 cv;
            cv[0] = f2bf(a.x); cv[1] = f2bf(a.y); cv[2] = f2bf(a.z); cv[3] = f2bf(a.w);
            cv[4] = f2bf(b.x); cv[5] = f2bf(b.y); cv[6] = f2bf(b.z); cv[7] = f2bf(b.w);
            afr[kc] = cv;
        }
    }

    const int srow_stat = t & 15, grp = t >> 4;

    #pragma unroll
    for (int m = 0; m < 3; ++m) {
        if (m) __syncthreads();        // prior lds_h readers done (B2/B4 cover; extra safe)
        #pragma unroll
        for (int cti = 0; cti < 4; ++cti) {
            const int ct = w * 4 + cti;
            const short* Brow = WT + ((size_t)m * NH + ct * 16 + rA) * ND + kg * 8;
            f32x4 acc = {0.f, 0.f, 0.f, 0.f};
            #pragma unroll
            for (int kc = 0; kc < 4; ++kc) {
                const bf16x8 bv = *(const bf16x8*)(Brow + kc * 32);
                acc = __builtin_amdgcn_mfma_f32_16x16x32_bf16(afr[kc], bv, acc, 0, 0, 0);
            }
            const int col = ct * 16 + rA;
            const float add = (m == 0) ? be1[col] : 0.f;
            #pragma unroll
            for (int q = 0; q < 4; ++q)
                lds_h[kg * 4 + q][col] = acc[q] + add;
        }
        __syncthreads();               // lds_h ready

        if (m < 2) {
            float* Fo = (m == 0) ? Pt : Qm;
            short* Bo = (m == 0) ? Pb : Qb;
            #pragma unroll 4
            for (int r = 0; r < 16; ++r) {
                const float val = lds_h[r][t];
                Fo[(size_t)(r0 + r) * NH + t] = val;
                Bo[(size_t)(r0 + r) * NH + t] = f2bf(val);
            }
            float s1 = 0.f, s2 = 0.f;
            #pragma unroll
            for (int c = grp * 16; c < grp * 16 + 16; ++c) {
                const float h = lds_h[srow_stat][c];
                s1 += h; s2 = fmaf(h, h, s2);
            }
            red1[srow_stat][grp] = s1; red2[srow_stat][grp] = s2;
            __syncthreads();           // red ready + lds_h reads done
            if (t < 16) {
                float S1 = 0.f, S2 = 0.f;
                #pragma unroll
                for (int g = 0; g < 16; ++g) { S1 += red1[t][g]; S2 += red2[t][g]; }
                if (m == 0) { stP1[t] = S1; stP2[t] = S2; }
                else        { stQ1[t] = S1; stQ2[t] = S2; }
            }
        } else {
            #pragma unroll 4
            for (int r = 0; r < 16; ++r)
                XW[(size_t)(r0 + r) * NH + t] = lds_h[r][t];
            if (t < 16)
                rowstats[r0 + t] = make_float4(stP1[t], stP2[t], stQ1[t], stQ2[t]);
        }
    }
}

// ---------------- K2: MFMA dot -> wmr table {0.5w, rr, -mu*rr, w} ----------------
__global__ __launch_bounds__(256) void k_dot(
    const short* __restrict__ Pb, const short* __restrict__ Qb,
    const float4* __restrict__ rowstats,
    const float* __restrict__ adj,
    float4* __restrict__ wmrG)
{
    const int b  = blockIdx.x >> 2;
    const int jt = blockIdx.x & 3;
    const int t  = threadIdx.x;
    const int l  = t & 63;
    const int i0 = (t >> 6) * 16;
    const int j0 = jt * 16;
    const int rA = l & 15;
    const int kg = l >> 4;

    const short* Prow = Pb + ((size_t)b * NN + i0 + rA) * NH + kg * 8;
    const short* Qrow = Qb + ((size_t)b * NN + j0 + rA) * NH + kg * 8;
    f32x4 acc = {0.f, 0.f, 0.f, 0.f};
    #pragma unroll
    for (int kc = 0; kc < 8; ++kc) {
        const bf16x8 av = *(const bf16x8*)(Prow + kc * 32);
        const bf16x8 bv = *(const bf16x8*)(Qrow + kc * 32);
        acc = __builtin_amdgcn_mfma_f32_16x16x32_bf16(av, bv, acc, 0, 0, 0);
    }
    const int j  = j0 + rA;
    const int gj = b * NN + j;
    const float4 stj = rowstats[gj];
    const float inv = 1.0f / NH;
    #pragma unroll
    for (int q = 0; q < 4; ++q) {
        const int i  = i0 + kg * 4 + q;
        const int gi = b * NN + i;
        const float4 sti = rowstats[gi];
        float a = adj[(size_t)gi * NN + j];
        if (j == i) a = 0.f;
        const float cd = acc[q];
        const float mu = (sti.x + stj.z) * inv;
        const float e2 = fmaf(2.f, cd, sti.y + stj.w) * inv;
        const float rr = __builtin_amdgcn_rsqf(fmaf(-mu, mu, e2) + LN_EPS);
        wmrG[(size_t)gi * NN + j] = make_float4(0.5f * a, rr, -mu * rr, a);
    }
}

// ---------------- K3: fused msg+node, 2 rows/block, 1024 blocks (R9-verbatim) ----------------
__global__ __launch_bounds__(256, 4) void k_mn(
    const float* __restrict__ slots,
    const float* __restrict__ Pt,
    const float* __restrict__ Qm,
    const float4* __restrict__ wmrG,
    const float* __restrict__ ge,  const float* __restrict__ bge,
    const float* __restrict__ XW,
    const float* __restrict__ WC, const float* __restrict__ v,
    const float* __restrict__ bn1,
    const float* __restrict__ gn,  const float* __restrict__ bgn,
    const float* __restrict__ Wn2, const float* __restrict__ bn2,
    float* __restrict__ out)
{
    union U {
        struct { float4 wmr[2][NN]; float s[4][2][NH]; } e;
        struct { float sfg[2][NH];
                 union { float part[2][4][NH]; float d[2][8][ND + 4]; } w; } n;
    };
    __shared__ U u;
    __shared__ float lds_ws[2];
    __shared__ float lds_red[4][2][2];
    __shared__ float lds_mr[2][2];

    const int row0 = blockIdx.x * 2;
    const int b    = row0 >> 6;
    const int t    = threadIdx.x;
    const int lane = t & 63;
    const int wave = t >> 6;

    const float xw0 = XW[(size_t)row0 * NH + t];
    const float xw1 = XW[(size_t)(row0 + 1) * NH + t];
    const float sl  = slots[(size_t)(row0 + (t >> 7)) * ND + (t & 127)];
    if (t < 128) {
        const int r = t >> 6, j = t & 63;
        u.e.wmr[r][j] = wmrG[(size_t)(row0 + r) * NN + j];
    }
    const float4 P0 = ((const float4*)(Pt + (size_t)row0 * NH))[lane];
    const float4 P1 = ((const float4*)(Pt + (size_t)(row0 + 1) * NH))[lane];
    const float4 G  = ((const float4*)ge)[lane];
    const float4 Bg = ((const float4*)bge)[lane];
    __syncthreads();

    if (wave < 2) {
        float wv = u.e.wmr[wave][lane].w;
        #pragma unroll
        for (int off = 32; off; off >>= 1) wv += __shfl_xor(wv, off);
        if (lane == 0) lds_ws[wave] = wv;
    }

    const float4* Qb4 = (const float4*)(Qm + (size_t)b * NN * NH) + lane;
    float4 A0 = make_float4(0.f, 0.f, 0.f, 0.f);
    float4 A1 = make_float4(0.f, 0.f, 0.f, 0.f);
    #pragma unroll 4
    for (int k = 0; k < 16; ++k) {
        const int jj = wave + 4 * k;
        const float4 q  = Qb4[jj * (NH / 4)];
        const float4 m0 = u.e.wmr[0][jj];
        const float4 m1 = u.e.wmr[1][jj];
        float h, uu;
        h = P0.x + q.x; uu = fmaf(fmaf(h, m0.y, m0.z), G.x, Bg.x); A0.x = fmaf(m0.x, gelu2(uu), A0.x);
        h = P0.y + q.y; uu = fmaf(fmaf(h, m0.y, m0.z), G.y, Bg.y); A0.y = fmaf(m0.x, gelu2(uu), A0.y);
        h = P0.z + q.z; uu = fmaf(fmaf(h, m0.y, m0.z), G.z, Bg.z); A0.z = fmaf(m0.x, gelu2(uu), A0.z);
        h = P0.w + q.w; uu = fmaf(fmaf(h, m0.y, m0.z), G.w, Bg.w); A0.w = fmaf(m0.x, gelu2(uu), A0.w);
        h = P1.x + q.x; uu = fmaf(fmaf(h, m1.y, m1.z), G.x, Bg.x); A1.x = fmaf(m1.x, gelu2(uu), A1.x);
        h = P1.y + q.y; uu = fmaf(fmaf(h, m1.y, m1.z), G.y, Bg.y); A1.y = fmaf(m1.x, gelu2(uu), A1.y);
        h = P1.z + q.z; uu = fmaf(fmaf(h, m1.y, m1.z), G.z, Bg.z); A1.z = fmaf(m1.x, gelu2(uu), A1.z);
        h = P1.w + q.w; uu = fmaf(fmaf(h, m1.y, m1.z), G.w, Bg.w); A1.w = fmaf(m1.x, gelu2(uu), A1.w);
    }
    ((float4*)u.e.s[wave][0])[lane] = A0;
    ((float4*)u.e.s[wave][1])[lane] = A1;
    __syncthreads();

    const float sf0 = (u.e.s[0][0][t] + u.e.s[1][0][t]) + (u.e.s[2][0][t] + u.e.s[3][0][t]);
    const float sf1 = (u.e.s[0][1][t] + u.e.s[1][1][t]) + (u.e.s[2][1][t] + u.e.s[3][1][t]);
    __syncthreads();
    u.n.sfg[0][t] = sf0;
    u.n.sfg[1][t] = sf1;
    __syncthreads();

    {
        const int ks = wave;
        const int cg = lane;
        float4 h0 = make_float4(0.f, 0.f, 0.f, 0.f);
        float4 h1 = make_float4(0.f, 0.f, 0.f, 0.f);
        const float4* wc4 = (const float4*)WC + cg;
        #pragma unroll 8
        for (int k = ks * 64; k < ks * 64 + 64; ++k) {
            const float4 wv = wc4[k * (NH / 4)];
            const float sa = u.n.sfg[0][k];
            const float sb = u.n.sfg[1][k];
            h0.x = fmaf(sa, wv.x, h0.x); h0.y = fmaf(sa, wv.y, h0.y);
            h0.z = fmaf(sa, wv.z, h0.z); h0.w = fmaf(sa, wv.w, h0.w);
            h1.x = fmaf(sb, wv.x, h1.x); h1.y = fmaf(sb, wv.y, h1.y);
            h1.z = fmaf(sb, wv.z, h1.z); h1.w = fmaf(sb, wv.w, h1.w);
        }
        ((float4*)u.n.w.part[0][ks])[cg] = h0;
        ((float4*)u.n.w.part[1][ks])[cg] = h1;
    }
    __syncthreads();

    float a0, a1;
    {
        const float b1 = bn1[t], vc = v[t];
        a0 = (u.n.w.part[0][0][t] + u.n.w.part[0][1][t])
           + (u.n.w.part[0][2][t] + u.n.w.part[0][3][t])
           + fmaf(lds_ws[0], vc, b1) + xw0;
        a1 = (u.n.w.part[1][0][t] + u.n.w.part[1][1][t])
           + (u.n.w.part[1][2][t] + u.n.w.part[1][3][t])
           + fmaf(lds_ws[1], vc, b1) + xw1;
    }
    {
        float s1 = a0, s2 = a0 * a0, s3 = a1, s4 = a1 * a1;
        #pragma unroll
        for (int off = 32; off; off >>= 1) {
            s1 += __shfl_xor(s1, off); s2 += __shfl_xor(s2, off);
            s3 += __shfl_xor(s3, off); s4 += __shfl_xor(s4, off);
        }
        if (lane == 0) {
            lds_red[wave][0][0] = s1; lds_red[wave][0][1] = s2;
            lds_red[wave][1][0] = s3; lds_red[wave][1][1] = s4;
        }
    }
    __syncthreads();
    if (t < 2) {
        const float S1 = (lds_red[0][t][0] + lds_red[1][t][0]) + (lds_red[2][t][0] + lds_red[3][t][0]);
        const float S2 = (lds_red[0][t][1] + lds_red[1][t][1]) + (lds_red[2][t][1] + lds_red[3][t][1]);
        const float mu  = S1 * (1.0f / NH);
        const float var = fmaf(-mu, mu, S2 * (1.0f / NH));
        lds_mr[t][0] = mu;
        lds_mr[t][1] = __builtin_amdgcn_rsqf(var + LN_EPS);
    }
    __syncthreads();
    {
        const float g = gn[t], bg = bgn[t];
        const float rr0 = lds_mr[0][1], rr1 = lds_mr[1][1];
        u.n.sfg[0][t] = gelu_h(fmaf(fmaf(a0, rr0, -lds_mr[0][0] * rr0), g, bg));
        u.n.sfg[1][t] = gelu_h(fmaf(fmaf(a1, rr1, -lds_mr[1][0] * rr1), g, bg));
    }
    __syncthreads();

    {
        const int ks = t >> 5;
        const int cg = t & 31;
        float4 d0 = make_float4(0.f, 0.f, 0.f, 0.f);
        float4 d1 = make_float4(0.f, 0.f, 0.f, 0.f);
        const float4* w2 = (const float4*)Wn2 + cg;
        const int kbeg = ks * 32;
        #pragma unroll 8
        for (int k = kbeg; k < kbeg + 32; ++k) {
            const float4 wv = w2[k * (ND / 4)];
            const float g0 = u.n.sfg[0][k];
            const float g1 = u.n.sfg[1][k];
            d0.x = fmaf(g0, wv.x, d0.x); d0.y = fmaf(g0, wv.y, d0.y);
            d0.z = fmaf(g0, wv.z, d0.z); d0.w = fmaf(g0, wv.w, d0.w);
            d1.x = fmaf(g1, wv.x, d1.x); d1.y = fmaf(g1, wv.y, d1.y);
            d1.z = fmaf(g1, wv.z, d1.z); d1.w = fmaf(g1, wv.w, d1.w);
        }
        ((float4*)u.n.w.d[0][ks])[cg] = d0;
        ((float4*)u.n.w.d[1][ks])[cg] = d1;
    }
    __syncthreads();
    {
        const int r  = t >> 7;
        const int c2 = t & 127;
        float ds = 0.f;
        #pragma unroll
        for (int p2 = 0; p2 < 8; ++p2) ds += u.n.w.d[r][p2][c2];
        out[(size_t)(row0 + r) * ND + c2] = sl + bn2[c2] + ds;
    }
}

extern "C" void kernel_launch(void* const* d_in, const int* in_sizes, int n_in,
                              void* d_out, int out_size, void* d_ws, size_t ws_size,
                              hipStream_t stream) {
    const float* slots = (const float*)d_in[0];
    const float* adj   = (const float*)d_in[1];
    const float* We1   = (const float*)d_in[2];
    const float* be1   = (const float*)d_in[3];
    const float* ge    = (const float*)d_in[4];
    const float* bge   = (const float*)d_in[5];
    const float* We2   = (const float*)d_in[6];
    const float* be2   = (const float*)d_in[7];
    const float* Wn1   = (const float*)d_in[8];
    const float* bn1   = (const float*)d_in[9];
    const float* gn    = (const float*)d_in[10];
    const float* bgn   = (const float*)d_in[11];
    const float* Wn2   = (const float*)d_in[12];
    const float* bn2   = (const float*)d_in[13];
    float* out = (float*)d_out;

    const size_t RN = (size_t)NB * NN;         // 2048
    float*  Ptw  = (float*)d_ws;               // [2048,256] f32
    float*  Qw   = Ptw  + RN * NH;             // [2048,256] f32
    float*  XWw  = Qw   + RN * NH;             // [2048,256] f32
    float*  WCw  = XWw  + RN * NH;             // [256,256]  f32
    float*  vw   = WCw  + (size_t)NH * NH;     // [256]
    float4* rsw  = (float4*)(vw + NH);         // [2048]
    float4* wmrw = rsw + RN;                   // [2048*64]
    short*  Pbw  = (short*)(wmrw + RN * NN);   // [2048,256] bf16
    short*  Qbw  = Pbw + RN * NH;              // [2048,256] bf16
    short*  WTw  = Qbw + RN * NH;              // [3,256,128] bf16

    k_prep<<<89,             256, 0, stream>>>(We1, Wn1, We2, be2, WCw, vw, WTw);
    k_pmm <<<(int)(RN / 16), 256, 0, stream>>>(slots, be1, WTw, Ptw, Qw, XWw, Pbw, Qbw, rsw);
    k_dot <<<NB * 4,         256, 0, stream>>>(Pbw, Qbw, rsw, adj, wmrw);
    k_mn  <<<(int)(RN / 2),  256, 0, stream>>>(slots, Ptw, Qw, wmrw, ge, bge,
                                               XWw, WCw, vw, bn1, gn, bgn, Wn2, bn2, out);
}

// Round 13
// 53.856 us; speedup vs baseline: 1.1744x; 1.1191x over previous
//
#include <hip/hip_runtime.h>

#define NB 32
#define NN 64
#define ND 128
#define NH 256
#define LN_EPS 1e-5f
#define RP 4

typedef __attribute__((ext_vector_type(8))) short bf16x8;
typedef __attribute__((ext_vector_type(4))) float f32x4;

// ---- branchless erf-based GELU, A&S 7.1.25 (|erf err| <= 5e-4), Estrin form ----
__device__ __forceinline__ float gelu2(float x) {     // returns 2*gelu(x)
    const float au  = fabsf(x);
    const float xpa = x + au;
    const float z   = au * 0.70710678118654752440f;
    const float z2  = z * z;
    const float pc  = fmaf(0.078108f, z, 0.000972f);
    const float pb  = fmaf(0.278393f, z, 1.0f);
    const float p   = fmaf(z2, fmaf(z, pc, 0.230389f), pb);
    const float p2  = p * p;
    const float r   = __builtin_amdgcn_rcpf(p2 * p2);
    return fmaf(-au, r, xpa);
}
__device__ __forceinline__ float gelu_h(float x) { return 0.5f * gelu2(x); }

__device__ __forceinline__ short f2bf(float f) {      // RNE float->bf16
    unsigned u = __float_as_uint(f);
    u += 0x7FFFu + ((u >> 16) & 1u);
    return (short)(u >> 16);
}
__device__ __forceinline__ float bflo(unsigned u) { return __uint_as_float(u << 16); }
__device__ __forceinline__ float bfhi(unsigned u) { return __uint_as_float(u & 0xFFFF0000u); }

// ---------------- K1: [0..511] Pt/Qm/XW/Pb/Qb + rowstats ; [512..580] WCb/v/Wn2b ----------------
__global__ __launch_bounds__(256) void k_pre(const float* __restrict__ slots,
                                             const float* __restrict__ We1,
                                             const float* __restrict__ be1,
                                             const float* __restrict__ Wn1,
                                             const float* __restrict__ We2,
                                             const float* __restrict__ be2,
                                             const float* __restrict__ Wn2,
                                             float* __restrict__ Pt,
                                             float* __restrict__ Qm,
                                             float* __restrict__ XW,
                                             short* __restrict__ Pb,
                                             short* __restrict__ Qb,
                                             float4* __restrict__ rowstats,
                                             unsigned short* __restrict__ WCb,
                                             float* __restrict__ v,
                                             unsigned short* __restrict__ Wn2b) {
    __shared__ float xs[RP][ND];
    __shared__ float red[4][RP][4];
    const int t = threadIdx.x;

    if (blockIdx.x >= 512) {           // ---- prep role ----
        const int bid2 = blockIdx.x - 512;
        if (bid2 == 64) {              // v = be2 @ Wn1_bot
            __shared__ float bs[ND];
            if (t < ND) bs[t] = be2[t];
            __syncthreads();
            float acc = 0.f;
            #pragma unroll 4
            for (int d = 0; d < ND; ++d) acc = fmaf(bs[d], Wn1[(ND + d) * NH + t], acc);
            v[t] = acc;
            return;
        }
        if (bid2 > 64) {               // Wn2b = bf16(Wn2), same [256][128] layout
            const int base = (bid2 - 65) * 8192;
            #pragma unroll 8
            for (int i = 0; i < 32; ++i) {
                const int idx = base + i * 256 + t;
                Wn2b[idx] = (unsigned short)f2bf(Wn2[idx]);
            }
            return;
        }
        const int k0 = bid2 * 4;       // WCb rows k0..k0+3 (bf16)
        __shared__ float ws[4][ND];
        #pragma unroll
        for (int i = 0; i < 2; ++i) {
            const int idx = t + i * 256;
            ws[idx >> 7][idx & 127] = We2[(k0 + (idx >> 7)) * ND + (idx & 127)];
        }
        __syncthreads();
        float acc[4] = {0.f, 0.f, 0.f, 0.f};
        #pragma unroll 4
        for (int d = 0; d < ND; ++d) {
            const float wn = Wn1[(ND + d) * NH + t];
            #pragma unroll
            for (int r = 0; r < 4; ++r) acc[r] = fmaf(ws[r][d], wn, acc[r]);
        }
        #pragma unroll
        for (int r = 0; r < 4; ++r)
            WCb[(size_t)(k0 + r) * NH + t] = (unsigned short)f2bf(acc[r]);
        return;
    }

    // ---- pq role ----
    const int r0 = blockIdx.x * RP;
    const int lane = t & 63, wave = t >> 6;
    #pragma unroll
    for (int i = 0; i < 2; ++i) {
        const int idx = t + i * 256;
        xs[idx >> 7][idx & 127] = slots[(size_t)(r0 + (idx >> 7)) * ND + (idx & 127)];
    }
    __syncthreads();
    float pt[RP], qq[RP], xw[RP];
    const float bb = be1[t];
    #pragma unroll
    for (int r = 0; r < RP; ++r) { pt[r] = bb; qq[r] = 0.f; xw[r] = 0.f; }
    #pragma unroll 4
    for (int d = 0; d < ND; ++d) {
        const float wt  = We1[d * NH + t];
        const float wbt = We1[(ND + d) * NH + t];
        const float wn  = Wn1[d * NH + t];
        #pragma unroll
        for (int r = 0; r < RP; ++r) {
            const float x = xs[r][d];
            pt[r] = fmaf(x, wt,  pt[r]);
            qq[r] = fmaf(x, wbt, qq[r]);
            xw[r] = fmaf(x, wn,  xw[r]);
        }
    }
    #pragma unroll
    for (int r = 0; r < RP; ++r) {
        const size_t row = (size_t)(r0 + r);
        Pt[row * NH + t] = pt[r];
        Qm[row * NH + t] = qq[r];
        XW[row * NH + t] = xw[r];
        Pb[row * NH + t] = f2bf(pt[r]);
        Qb[row * NH + t] = f2bf(qq[r]);
    }
    float s1[RP], s2[RP], s3[RP], s4[RP];
    #pragma unroll
    for (int r = 0; r < RP; ++r) {
        s1[r] = pt[r]; s2[r] = pt[r] * pt[r];
        s3[r] = qq[r]; s4[r] = qq[r] * qq[r];
    }
    #pragma unroll
    for (int off = 32; off; off >>= 1) {
        #pragma unroll
        for (int r = 0; r < RP; ++r) {
            s1[r] += __shfl_xor(s1[r], off);
            s2[r] += __shfl_xor(s2[r], off);
            s3[r] += __shfl_xor(s3[r], off);
            s4[r] += __shfl_xor(s4[r], off);
        }
    }
    if (lane == 0) {
        #pragma unroll
        for (int r = 0; r < RP; ++r) {
            red[wave][r][0] = s1[r]; red[wave][r][1] = s2[r];
            red[wave][r][2] = s3[r]; red[wave][r][3] = s4[r];
        }
    }
    __syncthreads();
    if (t < RP) {
        float4 st;
        st.x = (red[0][t][0] + red[1][t][0]) + (red[2][t][0] + red[3][t][0]);
        st.y = (red[0][t][1] + red[1][t][1]) + (red[2][t][1] + red[3][t][1]);
        st.z = (red[0][t][2] + red[1][t][2]) + (red[2][t][2] + red[3][t][2]);
        st.w = (red[0][t][3] + red[1][t][3]) + (red[2][t][3] + red[3][t][3]);
        rowstats[r0 + t] = st;
    }
}

// ---------------- K2: MFMA dot -> wmr table {0.5w, rr, -mu*rr, w} ----------------
__global__ __launch_bounds__(256) void k_dot(
    const short* __restrict__ Pb, const short* __restrict__ Qb,
    const float4* __restrict__ rowstats,
    const float* __restrict__ adj,
    float4* __restrict__ wmrG)
{
    const int b  = blockIdx.x >> 2;
    const int jt = blockIdx.x & 3;
    const int t  = threadIdx.x;
    const int l  = t & 63;
    const int i0 = (t >> 6) * 16;
    const int j0 = jt * 16;
    const int rA = l & 15;
    const int kg = l >> 4;

    const short* Prow = Pb + ((size_t)b * NN + i0 + rA) * NH + kg * 8;
    const short* Qrow = Qb + ((size_t)b * NN + j0 + rA) * NH + kg * 8;
    f32x4 acc = {0.f, 0.f, 0.f, 0.f};
    #pragma unroll
    for (int kc = 0; kc < 8; ++kc) {
        const bf16x8 av = *(const bf16x8*)(Prow + kc * 32);
        const bf16x8 bv = *(const bf16x8*)(Qrow + kc * 32);
        acc = __builtin_amdgcn_mfma_f32_16x16x32_bf16(av, bv, acc, 0, 0, 0);
    }
    const int j  = j0 + rA;
    const int gj = b * NN + j;
    const float4 stj = rowstats[gj];
    const float inv = 1.0f / NH;
    #pragma unroll
    for (int q = 0; q < 4; ++q) {
        const int i  = i0 + kg * 4 + q;
        const int gi = b * NN + i;
        const float4 sti = rowstats[gi];
        float a = adj[(size_t)gi * NN + j];
        if (j == i) a = 0.f;
        const float cd = acc[q];
        const float mu = (sti.x + stj.z) * inv;
        const float e2 = fmaf(2.f, cd, sti.y + stj.w) * inv;
        const float rr = __builtin_amdgcn_rsqf(fmaf(-mu, mu, e2) + LN_EPS);
        wmrG[(size_t)gi * NN + j] = make_float4(0.5f * a, rr, -mu * rr, a);
    }
}

// ---------------- K3: fused msg+node, 2 rows/block, 1024 blocks ----------------
__global__ __launch_bounds__(256, 4) void k_mn(
    const float* __restrict__ slots,
    const float* __restrict__ Pt,
    const float* __restrict__ Qm,
    const float4* __restrict__ wmrG,
    const float* __restrict__ ge,  const float* __restrict__ bge,
    const float* __restrict__ XW,
    const unsigned short* __restrict__ WCb, const float* __restrict__ v,
    const float* __restrict__ bn1,
    const float* __restrict__ gn,  const float* __restrict__ bgn,
    const unsigned short* __restrict__ Wn2b, const float* __restrict__ bn2,
    float* __restrict__ out)
{
    union U {
        struct { float4 wmr[2][NN]; float s[4][2][NH]; } e;
        struct { float sfg[2][NH];
                 union { float part[2][4][NH]; float d[2][8][ND + 4]; } w; } n;
    };
    __shared__ U u;
    __shared__ float lds_ws[2];
    __shared__ float lds_red[4][2][2];
    __shared__ float lds_mr[2][2];

    const int row0 = blockIdx.x * 2;
    const int b    = row0 >> 6;
    const int t    = threadIdx.x;
    const int lane = t & 63;
    const int wave = t >> 6;

    const float xw0 = XW[(size_t)row0 * NH + t];
    const float xw1 = XW[(size_t)(row0 + 1) * NH + t];
    const float sl  = slots[(size_t)(row0 + (t >> 7)) * ND + (t & 127)];
    if (t < 128) {
        const int r = t >> 6, j = t & 63;
        u.e.wmr[r][j] = wmrG[(size_t)(row0 + r) * NN + j];
    }
    const float4 P0 = ((const float4*)(Pt + (size_t)row0 * NH))[lane];
    const float4 P1 = ((const float4*)(Pt + (size_t)(row0 + 1) * NH))[lane];
    const float4 G  = ((const float4*)ge)[lane];
    const float4 Bg = ((const float4*)bge)[lane];
    __syncthreads();

    if (wave < 2) {
        float wv = u.e.wmr[wave][lane].w;
        #pragma unroll
        for (int off = 32; off; off >>= 1) wv += __shfl_xor(wv, off);
        if (lane == 0) lds_ws[wave] = wv;
    }

    const float4* Qb4 = (const float4*)(Qm + (size_t)b * NN * NH) + lane;
    float4 A0 = make_float4(0.f, 0.f, 0.f, 0.f);
    float4 A1 = make_float4(0.f, 0.f, 0.f, 0.f);
    #pragma unroll 4
    for (int k = 0; k < 16; ++k) {
        const int jj = wave + 4 * k;
        const float4 q  = Qb4[jj * (NH / 4)];
        const float4 m0 = u.e.wmr[0][jj];
        const float4 m1 = u.e.wmr[1][jj];
        float h, uu;
        h = P0.x + q.x; uu = fmaf(fmaf(h, m0.y, m0.z), G.x, Bg.x); A0.x = fmaf(m0.x, gelu2(uu), A0.x);
        h = P0.y + q.y; uu = fmaf(fmaf(h, m0.y, m0.z), G.y, Bg.y); A0.y = fmaf(m0.x, gelu2(uu), A0.y);
        h = P0.z + q.z; uu = fmaf(fmaf(h, m0.y, m0.z), G.z, Bg.z); A0.z = fmaf(m0.x, gelu2(uu), A0.z);
        h = P0.w + q.w; uu = fmaf(fmaf(h, m0.y, m0.z), G.w, Bg.w); A0.w = fmaf(m0.x, gelu2(uu), A0.w);
        h = P1.x + q.x; uu = fmaf(fmaf(h, m1.y, m1.z), G.x, Bg.x); A1.x = fmaf(m1.x, gelu2(uu), A1.x);
        h = P1.y + q.y; uu = fmaf(fmaf(h, m1.y, m1.z), G.y, Bg.y); A1.y = fmaf(m1.x, gelu2(uu), A1.y);
        h = P1.z + q.z; uu = fmaf(fmaf(h, m1.y, m1.z), G.z, Bg.z); A1.z = fmaf(m1.x, gelu2(uu), A1.z);
        h = P1.w + q.w; uu = fmaf(fmaf(h, m1.y, m1.z), G.w, Bg.w); A1.w = fmaf(m1.x, gelu2(uu), A1.w);
    }
    ((float4*)u.e.s[wave][0])[lane] = A0;
    ((float4*)u.e.s[wave][1])[lane] = A1;
    __syncthreads();

    const float sf0 = (u.e.s[0][0][t] + u.e.s[1][0][t]) + (u.e.s[2][0][t] + u.e.s[3][0][t]);
    const float sf1 = (u.e.s[0][1][t] + u.e.s[1][1][t]) + (u.e.s[2][1][t] + u.e.s[3][1][t]);
    __syncthreads();
    u.n.sfg[0][t] = sf0;
    u.n.sfg[1][t] = sf1;
    __syncthreads();

    // ---- WC GEMV: bf16 weights, 4-way k-split ----
    {
        const int ks = wave;
        const int cg = lane;
        float4 h0 = make_float4(0.f, 0.f, 0.f, 0.f);
        float4 h1 = make_float4(0.f, 0.f, 0.f, 0.f);
        const uint2* wc2 = (const uint2*)WCb + cg;     // row = 64 uint2
        #pragma unroll 8
        for (int k = ks * 64; k < ks * 64 + 64; ++k) {
            const uint2 wp = wc2[k * 64];
            const float w0 = bflo(wp.x), w1 = bfhi(wp.x);
            const float w2v = bflo(wp.y), w3 = bfhi(wp.y);
            const float sa = u.n.sfg[0][k];
            const float sb = u.n.sfg[1][k];
            h0.x = fmaf(sa, w0, h0.x); h0.y = fmaf(sa, w1, h0.y);
            h0.z = fmaf(sa, w2v, h0.z); h0.w = fmaf(sa, w3, h0.w);
            h1.x = fmaf(sb, w0, h1.x); h1.y = fmaf(sb, w1, h1.y);
            h1.z = fmaf(sb, w2v, h1.z); h1.w = fmaf(sb, w3, h1.w);
        }
        ((float4*)u.n.w.part[0][ks])[cg] = h0;
        ((float4*)u.n.w.part[1][ks])[cg] = h1;
    }
    __syncthreads();

    float a0, a1;
    {
        const float b1 = bn1[t], vc = v[t];
        a0 = (u.n.w.part[0][0][t] + u.n.w.part[0][1][t])
           + (u.n.w.part[0][2][t] + u.n.w.part[0][3][t])
           + fmaf(lds_ws[0], vc, b1) + xw0;
        a1 = (u.n.w.part[1][0][t] + u.n.w.part[1][1][t])
           + (u.n.w.part[1][2][t] + u.n.w.part[1][3][t])
           + fmaf(lds_ws[1], vc, b1) + xw1;
    }
    {
        float s1 = a0, s2 = a0 * a0, s3 = a1, s4 = a1 * a1;
        #pragma unroll
        for (int off = 32; off; off >>= 1) {
            s1 += __shfl_xor(s1, off); s2 += __shfl_xor(s2, off);
            s3 += __shfl_xor(s3, off); s4 += __shfl_xor(s4, off);
        }
        if (lane == 0) {
            lds_red[wave][0][0] = s1; lds_red[wave][0][1] = s2;
            lds_red[wave][1][0] = s3; lds_red[wave][1][1] = s4;
        }
    }
    __syncthreads();
    if (t < 2) {
        const float S1 = (lds_red[0][t][0] + lds_red[1][t][0]) + (lds_red[2][t][0] + lds_red[3][t][0]);
        const float S2 = (lds_red[0][t][1] + lds_red[1][t][1]) + (lds_red[2][t][1] + lds_red[3][t][1]);
        const float mu  = S1 * (1.0f / NH);
        const float var = fmaf(-mu, mu, S2 * (1.0f / NH));
        lds_mr[t][0] = mu;
        lds_mr[t][1] = __builtin_amdgcn_rsqf(var + LN_EPS);
    }
    __syncthreads();
    {
        const float g = gn[t], bg = bgn[t];
        const float rr0 = lds_mr[0][1], rr1 = lds_mr[1][1];
        u.n.sfg[0][t] = gelu_h(fmaf(fmaf(a0, rr0, -lds_mr[0][0] * rr0), g, bg));
        u.n.sfg[1][t] = gelu_h(fmaf(fmaf(a1, rr1, -lds_mr[1][0] * rr1), g, bg));
    }
    __syncthreads();

    // ---- delta = g @ Wn2 (bf16 weights, 8-way k-split, both rows) ----
    {
        const int ks = t >> 5;
        const int cg = t & 31;
        float4 d0 = make_float4(0.f, 0.f, 0.f, 0.f);
        float4 d1 = make_float4(0.f, 0.f, 0.f, 0.f);
        const uint2* w2b = (const uint2*)Wn2b + cg;    // row = 32 uint2
        const int kbeg = ks * 32;
        #pragma unroll 8
        for (int k = kbeg; k < kbeg + 32; ++k) {
            const uint2 wp = w2b[k * 32];
            const float w0 = bflo(wp.x), w1 = bfhi(wp.x);
            const float w2v = bflo(wp.y), w3 = bfhi(wp.y);
            const float g0 = u.n.sfg[0][k];
            const float g1 = u.n.sfg[1][k];
            d0.x = fmaf(g0, w0, d0.x); d0.y = fmaf(g0, w1, d0.y);
            d0.z = fmaf(g0, w2v, d0.z); d0.w = fmaf(g0, w3, d0.w);
            d1.x = fmaf(g1, w0, d1.x); d1.y = fmaf(g1, w1, d1.y);
            d1.z = fmaf(g1, w2v, d1.z); d1.w = fmaf(g1, w3, d1.w);
        }
        ((float4*)u.n.w.d[0][ks])[cg] = d0;
        ((float4*)u.n.w.d[1][ks])[cg] = d1;
    }
    __syncthreads();
    {
        const int r  = t >> 7;
        const int c2 = t & 127;
        float ds = 0.f;
        #pragma unroll
        for (int p2 = 0; p2 < 8; ++p2) ds += u.n.w.d[r][p2][c2];
        out[(size_t)(row0 + r) * ND + c2] = sl + bn2[c2] + ds;
    }
}

extern "C" void kernel_launch(void* const* d_in, const int* in_sizes, int n_in,
                              void* d_out, int out_size, void* d_ws, size_t ws_size,
                              hipStream_t stream) {
    const float* slots = (const float*)d_in[0];
    const float* adj   = (const float*)d_in[1];
    const float* We1   = (const float*)d_in[2];
    const float* be1   = (const float*)d_in[3];
    const float* ge    = (const float*)d_in[4];
    const float* bge   = (const float*)d_in[5];
    const float* We2   = (const float*)d_in[6];
    const float* be2   = (const float*)d_in[7];
    const float* Wn1   = (const float*)d_in[8];
    const float* bn1   = (const float*)d_in[9];
    const float* gn    = (const float*)d_in[10];
    const float* bgn   = (const float*)d_in[11];
    const float* Wn2   = (const float*)d_in[12];
    const float* bn2   = (const float*)d_in[13];
    float* out = (float*)d_out;

    const size_t RN = (size_t)NB * NN;          // 2048
    float*  Ptw  = (float*)d_ws;                // [2048,256] f32
    float*  Qw   = Ptw  + RN * NH;              // [2048,256] f32
    float*  XWw  = Qw   + RN * NH;              // [2048,256] f32
    float*  vw   = XWw  + RN * NH;              // [256]
    float4* rsw  = (float4*)(vw + NH + 768);    // [2048] (16B aligned: 256+768=1024 floats)
    float4* wmrw = rsw + RN;                    // [2048*64]
    short*  Pbw  = (short*)(wmrw + RN * NN);    // [2048,256] bf16
    short*  Qbw  = Pbw + RN * NH;               // [2048,256] bf16
    unsigned short* WCbw  = (unsigned short*)(Qbw + RN * NH);   // [256,256] bf16
    unsigned short* Wn2bw = WCbw + (size_t)NH * NH;             // [256,128] bf16

    k_pre<<<581,            256, 0, stream>>>(slots, We1, be1, Wn1, We2, be2, Wn2,
                                              Ptw, Qw, XWw, Pbw, Qbw, rsw, WCbw, vw, Wn2bw);
    k_dot<<<NB * 4,         256, 0, stream>>>(Pbw, Qbw, rsw, adj, wmrw);
    k_mn <<<(int)(RN / 2),  256, 0, stream>>>(slots, Ptw, Qw, wmrw, ge, bge,
                                              XWw, WCbw, vw, bn1, gn, bgn, Wn2bw, bn2, out);
}